// Round 1
// baseline (1981.838 us; speedup 1.0000x reference)
//
#include <hip/hip_runtime.h>
#include <hip/hip_bf16.h>

// UnrolledRNN on MI355X (gfx950).
// Design: 16 blocks x 256 threads (4 waves). Block owns 16 batch rows for the
// whole sequence. Wave w owns hidden-slice j in [32w, 32w+32).
// Per step t: h_new[b,j] = tanh( b_xh[j] + sum_i x[b,t,i] Wxh[i,j] + sum_k h[b,k] Whh[k,j] )
// computed as D[j,b] = Wxh^T . x_t^T + Whh^T . h^T via mfma_f32_16x16x32_bf16.
// - Weights live in registers as A-fragments (per-wave j-slice).
// - h lives in LDS (bf16, [16][128], XOR-swizzled, double buffered).
// - x_t staged in registers, prefetched 2 steps ahead (covers HBM latency).
// - raw s_barrier + manual lgkmcnt(0): avoids __syncthreads' vmcnt(0) drain
//   which would serialize the global prefetch.

#define SEQ  2048
#define HID  128
#define BD   16

typedef __attribute__((ext_vector_type(8))) short    short8;
typedef __attribute__((ext_vector_type(4))) float    f32x4;
typedef __attribute__((ext_vector_type(4))) float    f4;
typedef __attribute__((ext_vector_type(2))) unsigned u32x2;

union F8 { unsigned u[4]; short8 s; };

__device__ __forceinline__ unsigned pkbf(float a, float b) {
    union { __hip_bfloat16 h[2]; unsigned u; } t;
    t.h[0] = __float2bfloat16(a);
    t.h[1] = __float2bfloat16(b);
    return t.u;
}

__device__ __forceinline__ float tanh_fast(float x) {
    // tanh(x) = 1 - 2/(e^{2x}+1), e^{2x} = exp2(x * 2*log2(e))
    float e = __builtin_amdgcn_exp2f(x * 2.8853900817779268f);
    return 1.0f - 2.0f * __builtin_amdgcn_rcpf(e + 1.0f);
}

__device__ __forceinline__ void block_sync() {
    asm volatile("s_waitcnt lgkmcnt(0)" ::: "memory");
    __builtin_amdgcn_s_barrier();
    asm volatile("" ::: "memory");
}

#define MFMA16(A,B,C) __builtin_amdgcn_mfma_f32_16x16x32_bf16((A),(B),(C),0,0,0)

// One recurrence step. SLOT holds x_t (8 x f4). P = t&1 (compile-time),
// POFF = (t%2)+2 : register-slot reload offset for x_{t+2}. TRT = runtime t.
#define RNN_STEP(SLOT, P, POFF, TRT)                                          \
    {                                                                          \
        /* convert x_t to B-fragments (k = 32c + 8*lg + e) */                  \
        F8 xf[4];                                                              \
        _Pragma("unroll")                                                      \
        for (int c = 0; c < 4; ++c) {                                          \
            xf[c].u[0] = pkbf(SLOT[2*c][0],   SLOT[2*c][1]);                   \
            xf[c].u[1] = pkbf(SLOT[2*c][2],   SLOT[2*c][3]);                   \
            xf[c].u[2] = pkbf(SLOT[2*c+1][0], SLOT[2*c+1][1]);                 \
            xf[c].u[3] = pkbf(SLOT[2*c+1][2], SLOT[2*c+1][3]);                 \
        }                                                                      \
        /* reload slot with x_{t+2} (2-iteration flight) */                    \
        if ((TRT) + 2 < SEQ) {                                                 \
            _Pragma("unroll")                                                  \
            for (int c = 0; c < 4; ++c) {                                      \
                SLOT[2*c]   = *(const f4*)(xq + (POFF)*HID + 32*c);            \
                SLOT[2*c+1] = *(const f4*)(xq + (POFF)*HID + 32*c + 4);        \
            }                                                                  \
        }                                                                      \
        /* xh part: independent of h -> before the barrier */                  \
        f32x4 a0 = {bx[0][0], bx[0][1], bx[0][2], bx[0][3]};                   \
        f32x4 a1 = {bx[1][0], bx[1][1], bx[1][2], bx[1][3]};                   \
        _Pragma("unroll")                                                      \
        for (int c = 0; c < 4; ++c) {                                          \
            a0 = MFMA16(wxh[0][c], xf[c].s, a0);                               \
            a1 = MFMA16(wxh[1][c], xf[c].s, a1);                               \
        }                                                                      \
        block_sync(); /* h_t visible in Hbuf[P] */                             \
        _Pragma("unroll")                                                      \
        for (int c = 0; c < 4; ++c) {                                          \
            short8 hf = *reinterpret_cast<const short8*>(lds + (P)*4096 + rd[c]); \
            a0 = MFMA16(whh[0][c], hf, a0);                                    \
            a1 = MFMA16(whh[1][c], hf, a1);                                    \
        }                                                                      \
        /* tanh + pack + store h_{t+1} to the other buffer */                  \
        u32x2 w0, w1;                                                          \
        w0[0] = pkbf(tanh_fast(a0[0]), tanh_fast(a0[1]));                      \
        w0[1] = pkbf(tanh_fast(a0[2]), tanh_fast(a0[3]));                      \
        w1[0] = pkbf(tanh_fast(a1[0]), tanh_fast(a1[1]));                      \
        w1[1] = pkbf(tanh_fast(a1[2]), tanh_fast(a1[3]));                      \
        *reinterpret_cast<u32x2*>(lds + ((P)^1)*4096 + hw[0]) = w0;            \
        *reinterpret_cast<u32x2*>(lds + ((P)^1)*4096 + hw[1]) = w1;            \
    }

__launch_bounds__(256, 1)
__global__ void rnn_fused_kernel(const float* __restrict__ x,
                                 const float* __restrict__ h0,
                                 const float* __restrict__ Wxh,
                                 const float* __restrict__ bxh,
                                 const float* __restrict__ Whh,
                                 const float* __restrict__ Wout,
                                 const float* __restrict__ bout,
                                 float* __restrict__ out)
{
    __shared__ __align__(16) char lds[2 * 4096];  // Hbuf[2][16][128] bf16, swizzled

    const int tid  = threadIdx.x;
    const int wv   = tid >> 6;        // wave 0..3, owns j in [32*wv, 32*wv+32)
    const int lane = tid & 63;
    const int lg   = lane >> 4;       // 0..3
    const int lm   = lane & 15;       // 0..15
    const int b0   = blockIdx.x * BD;

    // ---- weight A-fragments: frag[T][c] elem e = W[(32c+8lg+e)][32wv+16T+lm]
    short8 wxh[2][4], whh[2][4];
    {
        const int col = 32*wv + lm;
        #pragma unroll
        for (int T = 0; T < 2; ++T) {
            #pragma unroll
            for (int c = 0; c < 4; ++c) {
                F8 fx, fh;
                #pragma unroll
                for (int e2 = 0; e2 < 4; ++e2) {
                    int k = 32*c + 8*lg + 2*e2;
                    fx.u[e2] = pkbf(Wxh[(size_t)k*HID + col + 16*T],
                                    Wxh[(size_t)(k+1)*HID + col + 16*T]);
                    fh.u[e2] = pkbf(Whh[(size_t)k*HID + col + 16*T],
                                    Whh[(size_t)(k+1)*HID + col + 16*T]);
                }
                wxh[T][c] = fx.s; whh[T][c] = fh.s;
            }
        }
    }

    // ---- bias into accumulator layout: acc reg r <-> j = 32wv + 16T + 4lg + r
    float bx[2][4];
    #pragma unroll
    for (int T = 0; T < 2; ++T)
        #pragma unroll
        for (int r = 0; r < 4; ++r)
            bx[T][r] = bxh[32*wv + 16*T + 4*lg + r];

    // ---- LDS addresses (loop-invariant; XOR swizzle byte ^= (row&7)<<4)
    int rd[4];
    #pragma unroll
    for (int c = 0; c < 4; ++c)
        rd[c] = (lm*256 + 64*c + 16*lg) ^ ((lm & 7) << 4);
    int hw[2];
    #pragma unroll
    for (int T = 0; T < 2; ++T)
        hw[T] = (lm*256 + 2*(32*wv + 16*T + 4*lg)) ^ ((lm & 7) << 4);

    // ---- init Hbuf[0] from h0 (each thread writes 8 bf16)
    {
        int b  = tid >> 4;            // 0..15
        int j0 = (tid & 15) * 8;      // 0..120
        const float* hp = h0 + (size_t)(b0 + b) * HID + j0;
        f4 v0 = *(const f4*)(hp);
        f4 v1 = *(const f4*)(hp + 4);
        F8 f;
        f.u[0] = pkbf(v0[0], v0[1]); f.u[1] = pkbf(v0[2], v0[3]);
        f.u[2] = pkbf(v1[0], v1[1]); f.u[3] = pkbf(v1[2], v1[3]);
        int off = (b*256 + 2*j0) ^ ((b & 7) << 4);
        *reinterpret_cast<short8*>(lds + off) = f.s;
    }

    // ---- x prefetch: lane reads x[b0+lm][t][32c+8lg .. +7]
    const float* xq = x + (size_t)(b0 + lm) * SEQ * HID + 8*lg;
    f4 sA[8], sB[8];
    #pragma unroll
    for (int c = 0; c < 4; ++c) {
        sA[2*c]   = *(const f4*)(xq + 32*c);
        sA[2*c+1] = *(const f4*)(xq + 32*c + 4);
        sB[2*c]   = *(const f4*)(xq + HID + 32*c);
        sB[2*c+1] = *(const f4*)(xq + HID + 32*c + 4);
    }

    // ---- main sequential loop
    for (int t = 0; t < SEQ; t += 2) {
        RNN_STEP(sA, 0, 2, t);
        RNN_STEP(sB, 1, 3, t + 1);
        xq += 2 * HID;
    }

    // ---- epilogue: out = h_last @ Wout + bout ; h_last is in Hbuf[0]
    block_sync();
    {
        short8 wo[2][4];
        const int col = 32*wv + lm;
        #pragma unroll
        for (int T = 0; T < 2; ++T) {
            #pragma unroll
            for (int c = 0; c < 4; ++c) {
                F8 f;
                #pragma unroll
                for (int e2 = 0; e2 < 4; ++e2) {
                    int k = 32*c + 8*lg + 2*e2;
                    f.u[e2] = pkbf(Wout[(size_t)k*HID + col + 16*T],
                                   Wout[(size_t)(k+1)*HID + col + 16*T]);
                }
                wo[T][c] = f.s;
            }
        }
        f32x4 o0 = {bout[32*wv + 4*lg + 0], bout[32*wv + 4*lg + 1],
                    bout[32*wv + 4*lg + 2], bout[32*wv + 4*lg + 3]};
        f32x4 o1 = {bout[32*wv + 16 + 4*lg + 0], bout[32*wv + 16 + 4*lg + 1],
                    bout[32*wv + 16 + 4*lg + 2], bout[32*wv + 16 + 4*lg + 3]};
        #pragma unroll
        for (int c = 0; c < 4; ++c) {
            short8 hf = *reinterpret_cast<const short8*>(lds + rd[c]);
            o0 = MFMA16(wo[0][c], hf, o0);
            o1 = MFMA16(wo[1][c], hf, o1);
        }
        float* op = out + (size_t)(b0 + lm) * HID + 32*wv + 4*lg;
        *reinterpret_cast<f4*>(op)      = o0;
        *reinterpret_cast<f4*>(op + 16) = o1;
    }
}

extern "C" void kernel_launch(void* const* d_in, const int* in_sizes, int n_in,
                              void* d_out, int out_size, void* d_ws, size_t ws_size,
                              hipStream_t stream) {
    const float* x    = (const float*)d_in[0];
    const float* h0   = (const float*)d_in[1];
    const float* Wxh  = (const float*)d_in[2];
    const float* bxh  = (const float*)d_in[3];
    const float* Whh  = (const float*)d_in[4];
    const float* Wout = (const float*)d_in[5];
    const float* bout = (const float*)d_in[6];
    (void)in_sizes; (void)n_in; (void)out_size; (void)d_ws; (void)ws_size;

    rnn_fused_kernel<<<dim3(256 / BD), dim3(256), 0, stream>>>(
        x, h0, Wxh, bxh, Whh, Wout, bout, (float*)d_out);
}

// Round 2
// 1031.748 us; speedup vs baseline: 1.9209x; 1.9209x over previous
//
#include <hip/hip_runtime.h>
#include <hip/hip_bf16.h>

// UnrolledRNN on MI355X (gfx950) — two-phase.
// Phase 1 (parallel, all CUs): xh[b,t,:] = x[b,t,:] @ Wxh + bxh  -> bf16 in d_ws.
// Phase 2 (serial, 16 blocks): h = tanh(xh_t + h @ Whh), scan over t; out proj.
// Phase 2 per-step critical path is minimized: xh prefetched 4 steps deep
// (L3-resident stream), only the hh MFMA 4-chain + tanh + LDS roundtrip remain.
// Falls back to the verified single-kernel version if ws is too small.

#define SEQ   2048
#define HID   128
#define BATCH 256
#define BD    16

typedef __attribute__((ext_vector_type(8))) short    short8;
typedef __attribute__((ext_vector_type(4))) float    f32x4;
typedef __attribute__((ext_vector_type(4))) float    f4;
typedef __attribute__((ext_vector_type(2))) unsigned u32x2;

union F8 { unsigned u[4]; short8 s; };

__device__ __forceinline__ unsigned pkbf(float a, float b) {
    union { __hip_bfloat16 h[2]; unsigned u; } t;
    t.h[0] = __float2bfloat16(a);
    t.h[1] = __float2bfloat16(b);
    return t.u;
}

__device__ __forceinline__ float blo(unsigned u) {
    union { unsigned v; float f; } t; t.v = u << 16; return t.f;
}
__device__ __forceinline__ float bhi(unsigned u) {
    union { unsigned v; float f; } t; t.v = u & 0xffff0000u; return t.f;
}

__device__ __forceinline__ float tanh_fast(float x) {
    float e = __builtin_amdgcn_exp2f(x * 2.8853900817779268f);
    return 1.0f - 2.0f * __builtin_amdgcn_rcpf(e + 1.0f);
}

__device__ __forceinline__ void block_sync() {
    asm volatile("s_waitcnt lgkmcnt(0)" ::: "memory");
    __builtin_amdgcn_s_barrier();
    asm volatile("" ::: "memory");
}

#define MFMA16(A,B,C) __builtin_amdgcn_mfma_f32_16x16x32_bf16((A),(B),(C),0,0,0)

// =====================================================================
// Phase 1: xh = x @ Wxh + bxh, bf16 output [BATCH*SEQ][HID] in ws.
// Grid-stride over 16-row tiles; wave-independent (no LDS, no barrier).
// D[j=16T+4lg+r][row=lm] per m89 C-layout; A elem e = Wxh[32c+8lg+e][16T+lm].
// =====================================================================
__launch_bounds__(256, 1)
__global__ void xh_gemm_kernel(const float* __restrict__ x,
                               const float* __restrict__ Wxh,
                               const float* __restrict__ bxh,
                               __hip_bfloat16* __restrict__ xh)
{
    const int tid  = threadIdx.x;
    const int wv   = tid >> 6;
    const int lane = tid & 63;
    const int lg   = lane >> 4;
    const int lm   = lane & 15;

    const int gw = blockIdx.x * 4 + wv;     // global wave id
    const int NW = gridDim.x * 4;           // total waves
    const int NT = (BATCH * SEQ) / 16;      // 32768 row-tiles

    // weight A-fragments: wa[T][c] elem e = Wxh[(32c+8lg+e)][16T+lm]
    short8 wa[8][4];
    {
        #pragma unroll
        for (int T = 0; T < 8; ++T) {
            #pragma unroll
            for (int c = 0; c < 4; ++c) {
                F8 f;
                #pragma unroll
                for (int e2 = 0; e2 < 4; ++e2) {
                    int k = 32*c + 8*lg + 2*e2;
                    f.u[e2] = pkbf(Wxh[(size_t)k*HID + 16*T + lm],
                                   Wxh[(size_t)(k+1)*HID + 16*T + lm]);
                }
                wa[T][c] = f.s;
            }
        }
    }
    // bias in acc layout: r -> j = 16T+4lg+r
    float bb[8][4];
    #pragma unroll
    for (int T = 0; T < 8; ++T)
        #pragma unroll
        for (int r = 0; r < 4; ++r)
            bb[T][r] = bxh[16*T + 4*lg + r];

    for (int tile = gw; tile < NT; tile += NW) {
        const float* xp = x + (size_t)tile*16*HID + (size_t)lm*HID + 8*lg;
        f4 s[8];
        #pragma unroll
        for (int c = 0; c < 4; ++c) {
            s[2*c]   = *(const f4*)(xp + 32*c);
            s[2*c+1] = *(const f4*)(xp + 32*c + 4);
        }
        F8 xf[4];
        #pragma unroll
        for (int c = 0; c < 4; ++c) {
            xf[c].u[0] = pkbf(s[2*c][0],   s[2*c][1]);
            xf[c].u[1] = pkbf(s[2*c][2],   s[2*c][3]);
            xf[c].u[2] = pkbf(s[2*c+1][0], s[2*c+1][1]);
            xf[c].u[3] = pkbf(s[2*c+1][2], s[2*c+1][3]);
        }
        __hip_bfloat16* op = xh + (size_t)(tile*16 + lm) * HID;
        #pragma unroll
        for (int T = 0; T < 8; ++T) {
            f32x4 acc = {bb[T][0], bb[T][1], bb[T][2], bb[T][3]};
            #pragma unroll
            for (int c = 0; c < 4; ++c)
                acc = MFMA16(wa[T][c], xf[c].s, acc);
            u32x2 w;
            w[0] = pkbf(acc[0], acc[1]);
            w[1] = pkbf(acc[2], acc[3]);
            *reinterpret_cast<u32x2*>(op + 16*T + 4*lg) = w;
        }
    }
}

// =====================================================================
// Phase 2: recurrence. 16 blocks x 4 waves; wave owns j in [32wv,32wv+32).
// Per step: acc <- xh_t (bf16, 4-step-deep prefetch); sync; h from LDS;
// 2x 4-chain hh MFMA; tanh; pack; store h to other LDS buffer.
// =====================================================================

#define REC_STEP(SLOT, P, POFF, TRT)                                          \
    {                                                                          \
        f32x4 a0, a1;                                                          \
        a0[0] = blo(SLOT[0][0]); a0[1] = bhi(SLOT[0][0]);                      \
        a0[2] = blo(SLOT[0][1]); a0[3] = bhi(SLOT[0][1]);                      \
        a1[0] = blo(SLOT[1][0]); a1[1] = bhi(SLOT[1][0]);                      \
        a1[2] = blo(SLOT[1][1]); a1[3] = bhi(SLOT[1][1]);                      \
        if ((TRT) + 4 < SEQ) {                                                 \
            SLOT[0] = *(const u32x2*)(xq + (POFF)*256);                        \
            SLOT[1] = *(const u32x2*)(xq + (POFF)*256 + 32);                   \
        }                                                                      \
        block_sync(); /* h_t visible in Hbuf[P] */                             \
        _Pragma("unroll")                                                      \
        for (int c = 0; c < 4; ++c) {                                          \
            short8 hf = *reinterpret_cast<const short8*>(lds + (P)*4096 + rd[c]); \
            a0 = MFMA16(whh[0][c], hf, a0);                                    \
            a1 = MFMA16(whh[1][c], hf, a1);                                    \
        }                                                                      \
        u32x2 w0, w1;                                                          \
        w0[0] = pkbf(tanh_fast(a0[0]), tanh_fast(a0[1]));                      \
        w0[1] = pkbf(tanh_fast(a0[2]), tanh_fast(a0[3]));                      \
        w1[0] = pkbf(tanh_fast(a1[0]), tanh_fast(a1[1]));                      \
        w1[1] = pkbf(tanh_fast(a1[2]), tanh_fast(a1[3]));                      \
        *reinterpret_cast<u32x2*>(lds + ((P)^1)*4096 + hw[0]) = w0;            \
        *reinterpret_cast<u32x2*>(lds + ((P)^1)*4096 + hw[1]) = w1;            \
    }

__launch_bounds__(256, 1)
__global__ void rnn_rec_kernel(const __hip_bfloat16* __restrict__ xh,
                               const float* __restrict__ h0,
                               const float* __restrict__ Whh,
                               const float* __restrict__ Wout,
                               const float* __restrict__ bout,
                               float* __restrict__ out)
{
    __shared__ __align__(16) char lds[2 * 4096];  // Hbuf[2][16][128] bf16, swizzled

    const int tid  = threadIdx.x;
    const int wv   = tid >> 6;
    const int lane = tid & 63;
    const int lg   = lane >> 4;
    const int lm   = lane & 15;
    const int b0   = blockIdx.x * BD;

    // Whh A-fragments
    short8 whh[2][4];
    {
        const int col = 32*wv + lm;
        #pragma unroll
        for (int T = 0; T < 2; ++T) {
            #pragma unroll
            for (int c = 0; c < 4; ++c) {
                F8 f;
                #pragma unroll
                for (int e2 = 0; e2 < 4; ++e2) {
                    int k = 32*c + 8*lg + 2*e2;
                    f.u[e2] = pkbf(Whh[(size_t)k*HID + col + 16*T],
                                   Whh[(size_t)(k+1)*HID + col + 16*T]);
                }
                whh[T][c] = f.s;
            }
        }
    }

    // LDS addresses (XOR swizzle byte ^= (row&7)<<4)
    int rd[4];
    #pragma unroll
    for (int c = 0; c < 4; ++c)
        rd[c] = (lm*256 + 64*c + 16*lg) ^ ((lm & 7) << 4);
    int hw[2];
    #pragma unroll
    for (int T = 0; T < 2; ++T)
        hw[T] = (lm*256 + 2*(32*wv + 16*T + 4*lg)) ^ ((lm & 7) << 4);

    // init Hbuf[0] from h0
    {
        int b  = tid >> 4;
        int j0 = (tid & 15) * 8;
        const float* hp = h0 + (size_t)(b0 + b) * HID + j0;
        f4 v0 = *(const f4*)(hp);
        f4 v1 = *(const f4*)(hp + 4);
        F8 f;
        f.u[0] = pkbf(v0[0], v0[1]); f.u[1] = pkbf(v0[2], v0[3]);
        f.u[2] = pkbf(v1[0], v1[1]); f.u[3] = pkbf(v1[2], v1[3]);
        int off = (b*256 + 2*j0) ^ ((b & 7) << 4);
        *reinterpret_cast<short8*>(lds + off) = f.s;
    }

    // xh stream: lane lm reads rows (b0+lm), 8 bf16 per step at j=32wv+16T+4lg
    const char* xq = (const char*)xh
                   + ((size_t)(b0 + lm) * SEQ) * (HID*2)
                   + (size_t)(32*wv + 4*lg) * 2;

    u32x2 pA[2], pB[2], pC[2], pD[2];
    pA[0] = *(const u32x2*)(xq + 0*256);      pA[1] = *(const u32x2*)(xq + 0*256 + 32);
    pB[0] = *(const u32x2*)(xq + 1*256);      pB[1] = *(const u32x2*)(xq + 1*256 + 32);
    pC[0] = *(const u32x2*)(xq + 2*256);      pC[1] = *(const u32x2*)(xq + 2*256 + 32);
    pD[0] = *(const u32x2*)(xq + 3*256);      pD[1] = *(const u32x2*)(xq + 3*256 + 32);

    for (int t = 0; t < SEQ; t += 4) {
        REC_STEP(pA, 0, 4, t);
        REC_STEP(pB, 1, 5, t + 1);
        REC_STEP(pC, 0, 6, t + 2);
        REC_STEP(pD, 1, 7, t + 3);
        xq += 4 * 256;
    }

    // epilogue: out = h_last @ Wout + bout ; h_last in Hbuf[0]
    block_sync();
    {
        short8 wo[2][4];
        const int col = 32*wv + lm;
        #pragma unroll
        for (int T = 0; T < 2; ++T) {
            #pragma unroll
            for (int c = 0; c < 4; ++c) {
                F8 f;
                #pragma unroll
                for (int e2 = 0; e2 < 4; ++e2) {
                    int k = 32*c + 8*lg + 2*e2;
                    f.u[e2] = pkbf(Wout[(size_t)k*HID + col + 16*T],
                                   Wout[(size_t)(k+1)*HID + col + 16*T]);
                }
                wo[T][c] = f.s;
            }
        }
        f32x4 o0 = {bout[32*wv + 4*lg + 0], bout[32*wv + 4*lg + 1],
                    bout[32*wv + 4*lg + 2], bout[32*wv + 4*lg + 3]};
        f32x4 o1 = {bout[32*wv + 16 + 4*lg + 0], bout[32*wv + 16 + 4*lg + 1],
                    bout[32*wv + 16 + 4*lg + 2], bout[32*wv + 16 + 4*lg + 3]};
        #pragma unroll
        for (int c = 0; c < 4; ++c) {
            short8 hf = *reinterpret_cast<const short8*>(lds + rd[c]);
            o0 = MFMA16(wo[0][c], hf, o0);
            o1 = MFMA16(wo[1][c], hf, o1);
        }
        float* op = out + (size_t)(b0 + lm) * HID + 32*wv + 4*lg;
        *reinterpret_cast<f4*>(op)      = o0;
        *reinterpret_cast<f4*>(op + 16) = o1;
    }
}

// =====================================================================
// Fallback: verified round-1 monolithic kernel (used if ws too small).
// =====================================================================
#define RNN_STEP(SLOT, P, POFF, TRT)                                          \
    {                                                                          \
        F8 xf[4];                                                              \
        _Pragma("unroll")                                                      \
        for (int c = 0; c < 4; ++c) {                                          \
            xf[c].u[0] = pkbf(SLOT[2*c][0],   SLOT[2*c][1]);                   \
            xf[c].u[1] = pkbf(SLOT[2*c][2],   SLOT[2*c][3]);                   \
            xf[c].u[2] = pkbf(SLOT[2*c+1][0], SLOT[2*c+1][1]);                 \
            xf[c].u[3] = pkbf(SLOT[2*c+1][2], SLOT[2*c+1][3]);                 \
        }                                                                      \
        if ((TRT) + 2 < SEQ) {                                                 \
            _Pragma("unroll")                                                  \
            for (int c = 0; c < 4; ++c) {                                      \
                SLOT[2*c]   = *(const f4*)(xq + (POFF)*HID + 32*c);            \
                SLOT[2*c+1] = *(const f4*)(xq + (POFF)*HID + 32*c + 4);        \
            }                                                                  \
        }                                                                      \
        f32x4 a0 = {bx[0][0], bx[0][1], bx[0][2], bx[0][3]};                   \
        f32x4 a1 = {bx[1][0], bx[1][1], bx[1][2], bx[1][3]};                   \
        _Pragma("unroll")                                                      \
        for (int c = 0; c < 4; ++c) {                                          \
            a0 = MFMA16(wxh[0][c], xf[c].s, a0);                               \
            a1 = MFMA16(wxh[1][c], xf[c].s, a1);                               \
        }                                                                      \
        block_sync();                                                          \
        _Pragma("unroll")                                                      \
        for (int c = 0; c < 4; ++c) {                                          \
            short8 hf = *reinterpret_cast<const short8*>(lds + (P)*4096 + rd[c]); \
            a0 = MFMA16(whh[0][c], hf, a0);                                    \
            a1 = MFMA16(whh[1][c], hf, a1);                                    \
        }                                                                      \
        u32x2 w0, w1;                                                          \
        w0[0] = pkbf(tanh_fast(a0[0]), tanh_fast(a0[1]));                      \
        w0[1] = pkbf(tanh_fast(a0[2]), tanh_fast(a0[3]));                      \
        w1[0] = pkbf(tanh_fast(a1[0]), tanh_fast(a1[1]));                      \
        w1[1] = pkbf(tanh_fast(a1[2]), tanh_fast(a1[3]));                      \
        *reinterpret_cast<u32x2*>(lds + ((P)^1)*4096 + hw[0]) = w0;            \
        *reinterpret_cast<u32x2*>(lds + ((P)^1)*4096 + hw[1]) = w1;            \
    }

__launch_bounds__(256, 1)
__global__ void rnn_fused_kernel(const float* __restrict__ x,
                                 const float* __restrict__ h0,
                                 const float* __restrict__ Wxh,
                                 const float* __restrict__ bxh,
                                 const float* __restrict__ Whh,
                                 const float* __restrict__ Wout,
                                 const float* __restrict__ bout,
                                 float* __restrict__ out)
{
    __shared__ __align__(16) char lds[2 * 4096];

    const int tid  = threadIdx.x;
    const int wv   = tid >> 6;
    const int lane = tid & 63;
    const int lg   = lane >> 4;
    const int lm   = lane & 15;
    const int b0   = blockIdx.x * BD;

    short8 wxh[2][4], whh[2][4];
    {
        const int col = 32*wv + lm;
        #pragma unroll
        for (int T = 0; T < 2; ++T) {
            #pragma unroll
            for (int c = 0; c < 4; ++c) {
                F8 fx, fh;
                #pragma unroll
                for (int e2 = 0; e2 < 4; ++e2) {
                    int k = 32*c + 8*lg + 2*e2;
                    fx.u[e2] = pkbf(Wxh[(size_t)k*HID + col + 16*T],
                                    Wxh[(size_t)(k+1)*HID + col + 16*T]);
                    fh.u[e2] = pkbf(Whh[(size_t)k*HID + col + 16*T],
                                    Whh[(size_t)(k+1)*HID + col + 16*T]);
                }
                wxh[T][c] = fx.s; whh[T][c] = fh.s;
            }
        }
    }
    float bx[2][4];
    #pragma unroll
    for (int T = 0; T < 2; ++T)
        #pragma unroll
        for (int r = 0; r < 4; ++r)
            bx[T][r] = bxh[32*wv + 16*T + 4*lg + r];

    int rd[4];
    #pragma unroll
    for (int c = 0; c < 4; ++c)
        rd[c] = (lm*256 + 64*c + 16*lg) ^ ((lm & 7) << 4);
    int hw[2];
    #pragma unroll
    for (int T = 0; T < 2; ++T)
        hw[T] = (lm*256 + 2*(32*wv + 16*T + 4*lg)) ^ ((lm & 7) << 4);

    {
        int b  = tid >> 4;
        int j0 = (tid & 15) * 8;
        const float* hp = h0 + (size_t)(b0 + b) * HID + j0;
        f4 v0 = *(const f4*)(hp);
        f4 v1 = *(const f4*)(hp + 4);
        F8 f;
        f.u[0] = pkbf(v0[0], v0[1]); f.u[1] = pkbf(v0[2], v0[3]);
        f.u[2] = pkbf(v1[0], v1[1]); f.u[3] = pkbf(v1[2], v1[3]);
        int off = (b*256 + 2*j0) ^ ((b & 7) << 4);
        *reinterpret_cast<short8*>(lds + off) = f.s;
    }

    const float* xq = x + (size_t)(b0 + lm) * SEQ * HID + 8*lg;
    f4 sA[8], sB[8];
    #pragma unroll
    for (int c = 0; c < 4; ++c) {
        sA[2*c]   = *(const f4*)(xq + 32*c);
        sA[2*c+1] = *(const f4*)(xq + 32*c + 4);
        sB[2*c]   = *(const f4*)(xq + HID + 32*c);
        sB[2*c+1] = *(const f4*)(xq + HID + 32*c + 4);
    }

    for (int t = 0; t < SEQ; t += 2) {
        RNN_STEP(sA, 0, 2, t);
        RNN_STEP(sB, 1, 3, t + 1);
        xq += 2 * HID;
    }

    block_sync();
    {
        short8 wo[2][4];
        const int col = 32*wv + lm;
        #pragma unroll
        for (int T = 0; T < 2; ++T) {
            #pragma unroll
            for (int c = 0; c < 4; ++c) {
                F8 f;
                #pragma unroll
                for (int e2 = 0; e2 < 4; ++e2) {
                    int k = 32*c + 8*lg + 2*e2;
                    f.u[e2] = pkbf(Wout[(size_t)k*HID + col + 16*T],
                                   Wout[(size_t)(k+1)*HID + col + 16*T]);
                }
                wo[T][c] = f.s;
            }
        }
        f32x4 o0 = {bout[32*wv + 4*lg + 0], bout[32*wv + 4*lg + 1],
                    bout[32*wv + 4*lg + 2], bout[32*wv + 4*lg + 3]};
        f32x4 o1 = {bout[32*wv + 16 + 4*lg + 0], bout[32*wv + 16 + 4*lg + 1],
                    bout[32*wv + 16 + 4*lg + 2], bout[32*wv + 16 + 4*lg + 3]};
        #pragma unroll
        for (int c = 0; c < 4; ++c) {
            short8 hf = *reinterpret_cast<const short8*>(lds + rd[c]);
            o0 = MFMA16(wo[0][c], hf, o0);
            o1 = MFMA16(wo[1][c], hf, o1);
        }
        float* op = out + (size_t)(b0 + lm) * HID + 32*wv + 4*lg;
        *reinterpret_cast<f4*>(op)      = o0;
        *reinterpret_cast<f4*>(op + 16) = o1;
    }
}

extern "C" void kernel_launch(void* const* d_in, const int* in_sizes, int n_in,
                              void* d_out, int out_size, void* d_ws, size_t ws_size,
                              hipStream_t stream) {
    const float* x    = (const float*)d_in[0];
    const float* h0   = (const float*)d_in[1];
    const float* Wxh  = (const float*)d_in[2];
    const float* bxh  = (const float*)d_in[3];
    const float* Whh  = (const float*)d_in[4];
    const float* Wout = (const float*)d_in[5];
    const float* bout = (const float*)d_in[6];
    (void)in_sizes; (void)n_in; (void)out_size;

    const size_t need = (size_t)BATCH * SEQ * HID * 2;  // 134 MB bf16 xh
    if (ws_size >= need) {
        __hip_bfloat16* xh = (__hip_bfloat16*)d_ws;
        xh_gemm_kernel<<<dim3(512), dim3(256), 0, stream>>>(x, Wxh, bxh, xh);
        rnn_rec_kernel<<<dim3(BATCH / BD), dim3(256), 0, stream>>>(
            xh, h0, Whh, Wout, bout, (float*)d_out);
    } else {
        rnn_fused_kernel<<<dim3(BATCH / BD), dim3(256), 0, stream>>>(
            x, h0, Wxh, bxh, Whh, Wout, bout, (float*)d_out);
    }
}